// Round 1
// baseline (1364.087 us; speedup 1.0000x reference)
//
#include <hip/hip_runtime.h>

// Problem constants (from reference):
//   B=100000, R1=1, N1=200, N2=200, N3=50, R2=32
//   TT_core: (1,200,200,50,32) f32  = 64,000,000 elems (256 MB)
//   K1,K2: (200,200) f32; K3: (50,50) f32; indices: (B,3) int (values in [0,50))
//   out = (T3 gathered)[B,1,32] (3.2M f32), reg = T3*TT (64M f32)
// d_out layout: [0,3.2M) out, [3.2M, 67.2M) reg.

#define N12   200
#define N3    50
#define R2    32
#define SJK   320000          // stride of i in TT == N2*N3*R2; also stride of a in T1
#define SKS   1600            // stride of j / b  == N3*R2
#define NTOT  64000000
#define NB    100000
#define OUT_ELEMS 3200000     // B*32

// ---------------------------------------------------------------- transpose
__global__ __launch_bounds__(256) void k_transpose(
    const float* __restrict__ K1, const float* __restrict__ K2,
    float* __restrict__ K1T, float* __restrict__ K2T) {
  int t = blockIdx.x * 256 + threadIdx.x;
  if (t < N12 * N12) {
    int i = t / N12, a = t % N12;          // t = i*200 + a
    K1T[t] = K1[a * N12 + i];
    K2T[t] = K2[a * N12 + i];
  }
}

// ------------------------------------------------- contract i: T1 = K1 x TT
// T1[a, m] = sum_i K1[a,i] * TT[i, m],  m in [0,320000)
// grid (1250, 4): x = m-tile of 256, y = a-tile of 50
__global__ __launch_bounds__(256) void k_contract_i(
    const float* __restrict__ TT, const float* __restrict__ K1T,
    float* __restrict__ T1) {
  const int m  = blockIdx.x * 256 + threadIdx.x;
  const int a0 = blockIdx.y * 50;
  float acc[50];
#pragma unroll
  for (int aa = 0; aa < 50; ++aa) acc[aa] = 0.f;
#pragma unroll 2
  for (int i = 0; i < N12; ++i) {
    float v = TT[i * SJK + m];
    const float* kr = K1T + i * N12 + a0;   // wave-uniform -> s_load
#pragma unroll
    for (int aa = 0; aa < 50; ++aa) acc[aa] = fmaf(kr[aa], v, acc[aa]);
  }
#pragma unroll
  for (int aa = 0; aa < 50; ++aa) T1[(a0 + aa) * SJK + m] = acc[aa];
}

// ------------------------------------------------- contract j: T2 = K2 x T1
// T2[a, b, m2] = sum_j K2[b,j] * T1[a, j, m2],  m2 in [0,1600)
// grid (5, 200, 4): x = m2-tile of 320, y = a, z = b-tile of 50
__global__ __launch_bounds__(320) void k_contract_j(
    const float* __restrict__ T1, const float* __restrict__ K2T,
    float* __restrict__ T2) {
  const int m2   = blockIdx.x * 320 + threadIdx.x;
  const int a    = blockIdx.y;
  const int b0   = blockIdx.z * 50;
  const int base = a * SJK;
  float acc[50];
#pragma unroll
  for (int bb = 0; bb < 50; ++bb) acc[bb] = 0.f;
#pragma unroll 2
  for (int j = 0; j < N12; ++j) {
    float v = T1[base + j * SKS + m2];
    const float* kr = K2T + j * N12 + b0;   // wave-uniform -> s_load
#pragma unroll
    for (int bb = 0; bb < 50; ++bb) acc[bb] = fmaf(kr[bb], v, acc[bb]);
  }
#pragma unroll
  for (int bb = 0; bb < 50; ++bb) T2[base + (b0 + bb) * SKS + m2] = acc[bb];
}

// ---------------------- fallback contract j, in-place (ws too small path)
// grid (20, 200): x = m2-tile of 80, y = a. Reads T12[a, all j, m2-tile]
// into LDS, then overwrites the same addresses with T2. Per-block-private
// address set + __syncthreads -> safe in place.
__global__ __launch_bounds__(256) void k_contract_j_inplace(
    float* T12, const float* __restrict__ K2T) {
  __shared__ float lds[N12 * 80];   // 64000 B
  const int a    = blockIdx.y;
  const int m0   = blockIdx.x * 80;
  const int base = a * SJK + m0;
  for (int t = threadIdx.x; t < N12 * 80; t += 256) {
    int j = t / 80, ml = t % 80;
    lds[t] = T12[base + j * SKS + ml];
  }
  __syncthreads();
  for (int o = threadIdx.x; o < N12 * 80; o += 256) {
    int b = o / 80, ml = o % 80;
    float acc = 0.f;
#pragma unroll 4
    for (int j = 0; j < N12; ++j)
      acc = fmaf(K2T[j * N12 + b], lds[j * 80 + ml], acc);
    T12[base + b * SKS + ml] = acc;
  }
}

// ------------- gather: out[n,s] = sum_k K3[c,k] * T2[a,b,k,s]  (a,b,c < 50)
__global__ __launch_bounds__(256) void k_gather(
    const float* T2, const float* __restrict__ K3,
    const int* __restrict__ idx, float* __restrict__ out) {
  int g = blockIdx.x * 256 + threadIdx.x;   // 3.2M threads exactly
  int n = g >> 5, s = g & 31;
  int a = idx[n * 3 + 0], b = idx[n * 3 + 1], c = idx[n * 3 + 2];
  const float* t2  = T2 + a * SJK + b * SKS + s;
  const float* k3r = K3 + c * N3;
  float acc = 0.f;
#pragma unroll
  for (int k = 0; k < N3; ++k) acc = fmaf(k3r[k], t2[k * R2], acc);
  out[g] = acc;
}

// ------- contract k + elementwise: reg[a,b,c,s] = (sum_k K3[c,k]*T2[a,b,k,s]) * TT[..]
// grid (200, 200): x = b, y = a. Stages the 1600-float T2 slab in LDS, then
// writes reg over the SAME slab (safe in place; needed for fallback path).
__global__ __launch_bounds__(320) void k_contract_k_reg(
    const float* T2, const float* __restrict__ TT,
    const float* __restrict__ K3, float* reg) {
  const int a = blockIdx.y, b = blockIdx.x;
  const int base = a * SJK + b * SKS;
  __shared__ float lds[SKS];
  for (int t = threadIdx.x; t < SKS; t += 320) lds[t] = T2[base + t];
  __syncthreads();
#pragma unroll
  for (int q = 0; q < 5; ++q) {
    int mm = q * 320 + threadIdx.x;
    int c = mm >> 5, s = mm & 31;
    const float* k3r = K3 + c * N3;
    float acc = 0.f;
#pragma unroll
    for (int k = 0; k < N3; ++k) acc = fmaf(k3r[k], lds[k * R2 + s], acc);
    reg[base + mm] = acc * TT[base + mm];
  }
}

extern "C" void kernel_launch(void* const* d_in, const int* in_sizes, int n_in,
                              void* d_out, int out_size, void* d_ws, size_t ws_size,
                              hipStream_t stream) {
  const float* TT  = (const float*)d_in[0];
  const float* K1  = (const float*)d_in[1];
  const float* K2  = (const float*)d_in[2];
  const float* K3  = (const float*)d_in[3];
  const int*   idx = (const int*)d_in[4];

  float* out = (float*)d_out;          // [0, 3.2M)
  float* reg = out + OUT_ELEMS;        // [3.2M, 67.2M) -- also T1/T2 scratch
  // K1T/K2T live in the out region (dead until k_gather, which runs after
  // both consumers have finished).
  float* k1t = out;                    // 40000 floats
  float* k2t = out + N12 * N12;        // 40000 floats

  k_transpose<<<dim3((N12 * N12 + 255) / 256), 256, 0, stream>>>(K1, K2, k1t, k2t);

  // contract i: T1 -> reg region (scratch)
  k_contract_i<<<dim3(SJK / 256, 4), 256, 0, stream>>>(TT, k1t, reg);

  const size_t need = (size_t)NTOT * sizeof(float);   // 256,000,000 B
  if (ws_size >= need) {
    float* T2 = (float*)d_ws;
    k_contract_j<<<dim3(5, N12, 4), 320, 0, stream>>>(reg, k2t, T2);
    k_gather<<<dim3(OUT_ELEMS / 256), 256, 0, stream>>>(T2, K3, idx, out);
    k_contract_k_reg<<<dim3(N12, N12), 320, 0, stream>>>(T2, TT, K3, reg);
  } else {
    // in-place fallback: T2 overwrites T1 inside the reg region
    k_contract_j_inplace<<<dim3(20, N12), 256, 0, stream>>>(reg, k2t);
    k_gather<<<dim3(OUT_ELEMS / 256), 256, 0, stream>>>(reg, K3, idx, out);
    k_contract_k_reg<<<dim3(N12, N12), 320, 0, stream>>>(reg, TT, K3, reg);
  }
}

// Round 2
// 927.232 us; speedup vs baseline: 1.4711x; 1.4711x over previous
//
#include <hip/hip_runtime.h>

// Problem constants (from reference):
//   B=100000, R1=1, N1=200, N2=200, N3=50, R2=32
//   TT_core: (1,200,200,50,32) f32  = 64,000,000 elems (256 MB)
//   K1,K2: (200,200) f32; K3: (50,50) f32; indices: (B,3) int (values in [0,50))
//   out = (T3 gathered)[B,1,32] (3.2M f32), reg = T3*TT (64M f32)
// d_out layout: [0,3.2M) out, [3.2M, 67.2M) reg.

#define N12   200
#define N3    50
#define R2    32
#define SJK   320000          // stride of i in TT == N2*N3*R2; also stride of a in T1
#define SKS   1600            // stride of j / b  == N3*R2
#define NTOT  64000000
#define NB    100000
#define OUT_ELEMS 3200000     // B*32

// ---------------------------------------------------------------- transpose
__global__ __launch_bounds__(256) void k_transpose(
    const float* __restrict__ K1, const float* __restrict__ K2,
    float* __restrict__ K1T, float* __restrict__ K2T) {
  int t = blockIdx.x * 256 + threadIdx.x;
  if (t < N12 * N12) {
    int i = t / N12, a = t % N12;          // t = i*200 + a
    K1T[t] = K1[a * N12 + i];
    K2T[t] = K2[a * N12 + i];
  }
}

// ------------------------------------------------- contract i: T1 = K1 x TT
// T1[a, m] = sum_i K1[a,i] * TT[i, m],  m in [0,320000)
// grid (1250, 4): x = m-tile of 256, y = a-tile of 50
__global__ __launch_bounds__(256) void k_contract_i(
    const float* __restrict__ TT, const float* __restrict__ K1T,
    float* __restrict__ T1) {
  const int m  = blockIdx.x * 256 + threadIdx.x;
  const int a0 = blockIdx.y * 50;
  float acc[50];
#pragma unroll
  for (int aa = 0; aa < 50; ++aa) acc[aa] = 0.f;
#pragma unroll 2
  for (int i = 0; i < N12; ++i) {
    float v = TT[i * SJK + m];
    const float* kr = K1T + i * N12 + a0;   // wave-uniform -> s_load
#pragma unroll
    for (int aa = 0; aa < 50; ++aa) acc[aa] = fmaf(kr[aa], v, acc[aa]);
  }
#pragma unroll
  for (int aa = 0; aa < 50; ++aa) T1[(a0 + aa) * SJK + m] = acc[aa];
}

// ------------------------------------------------- contract j: T2 = K2 x T1
// T2[a, b, m2] = sum_j K2[b,j] * T1[a, j, m2],  m2 in [0,1600)
// grid (5, 200, 4): x = m2-tile of 320, y = a, z = b-tile of 50
__global__ __launch_bounds__(320) void k_contract_j(
    const float* __restrict__ T1, const float* __restrict__ K2T,
    float* __restrict__ T2) {
  const int m2   = blockIdx.x * 320 + threadIdx.x;
  const int a    = blockIdx.y;
  const int b0   = blockIdx.z * 50;
  const int base = a * SJK;
  float acc[50];
#pragma unroll
  for (int bb = 0; bb < 50; ++bb) acc[bb] = 0.f;
#pragma unroll 2
  for (int j = 0; j < N12; ++j) {
    float v = T1[base + j * SKS + m2];
    const float* kr = K2T + j * N12 + b0;   // wave-uniform -> s_load
#pragma unroll
    for (int bb = 0; bb < 50; ++bb) acc[bb] = fmaf(kr[bb], v, acc[bb]);
  }
#pragma unroll
  for (int bb = 0; bb < 50; ++bb) T2[base + (b0 + bb) * SKS + m2] = acc[bb];
}

// ---------------------- fallback contract j, in-place (ws too small path)
// grid (20, 200): x = m2-tile of 80, y = a. Reads T12[a, all j, m2-tile]
// into LDS, then overwrites the same addresses with T2. Per-block-private
// address set + __syncthreads -> safe in place.
__global__ __launch_bounds__(256) void k_contract_j_inplace(
    float* T12, const float* __restrict__ K2T) {
  __shared__ float lds[N12 * 80];   // 64000 B
  const int a    = blockIdx.y;
  const int m0   = blockIdx.x * 80;
  const int base = a * SJK + m0;
  for (int t = threadIdx.x; t < N12 * 80; t += 256) {
    int j = t / 80, ml = t % 80;
    lds[t] = T12[base + j * SKS + ml];
  }
  __syncthreads();
  for (int o = threadIdx.x; o < N12 * 80; o += 256) {
    int b = o / 80, ml = o % 80;
    float acc = 0.f;
#pragma unroll 4
    for (int j = 0; j < N12; ++j)
      acc = fmaf(K2T[j * N12 + b], lds[j * 80 + ml], acc);
    T12[base + b * SKS + ml] = acc;
  }
}

// ------------- gather: out[n,s] = sum_k K3[c,k] * T2[a,b,k,s]  (a,b,c < 50)
__global__ __launch_bounds__(256) void k_gather(
    const float* T2, const float* __restrict__ K3,
    const int* __restrict__ idx, float* __restrict__ out) {
  int g = blockIdx.x * 256 + threadIdx.x;   // 3.2M threads exactly
  int n = g >> 5, s = g & 31;
  int a = idx[n * 3 + 0], b = idx[n * 3 + 1], c = idx[n * 3 + 2];
  const float* t2  = T2 + a * SJK + b * SKS + s;
  const float* k3r = K3 + c * N3;
  float acc = 0.f;
#pragma unroll
  for (int k = 0; k < N3; ++k) acc = fmaf(k3r[k], t2[k * R2], acc);
  out[g] = acc;
}

// ------- contract k + elementwise: reg[a,b,c,s] = (sum_k K3[c,k]*T2[a,b,k,s]) * TT[..]
// NO LDS: each thread owns one (a,b,s) column. Loads the 50 k-values into
// VGPRs (coalesced 128B segments per half-wave), then 50x50 register FMAs
// against wave-uniform K3 rows (s_load). 2 split accumulators break the
// dep chain. In-place safe (fallback path: reg==T2): each half-wave owns
// its slab exclusively and all v[k] loads complete before the first store
// (store depends on acc which depends on every v). T2/reg NOT __restrict__.
__global__ __launch_bounds__(256) void k_contract_k_reg(
    const float* T2, const float* __restrict__ TT,
    const float* __restrict__ K3, float* reg) {
  const int t  = blockIdx.x * 256 + threadIdx.x;  // 1.28M threads = 40000*32
  const int s  = t & 31;
  const int ab = t >> 5;                          // 0..39999
  const int base = ab * SKS + s;
  float v[N3];
#pragma unroll
  for (int k = 0; k < N3; ++k) v[k] = T2[base + k * R2];
  for (int c = 0; c < N3; ++c) {
    const float* k3r = K3 + c * N3;               // wave-uniform -> s_load
    float acc0 = 0.f, acc1 = 0.f;
#pragma unroll
    for (int k = 0; k < N3; k += 2) {
      acc0 = fmaf(k3r[k], v[k], acc0);
      acc1 = fmaf(k3r[k + 1], v[k + 1], acc1);
    }
    const int o = base + c * R2;
    reg[o] = (acc0 + acc1) * TT[o];
  }
}

extern "C" void kernel_launch(void* const* d_in, const int* in_sizes, int n_in,
                              void* d_out, int out_size, void* d_ws, size_t ws_size,
                              hipStream_t stream) {
  const float* TT  = (const float*)d_in[0];
  const float* K1  = (const float*)d_in[1];
  const float* K2  = (const float*)d_in[2];
  const float* K3  = (const float*)d_in[3];
  const int*   idx = (const int*)d_in[4];

  float* out = (float*)d_out;          // [0, 3.2M)
  float* reg = out + OUT_ELEMS;        // [3.2M, 67.2M) -- also T1/T2 scratch
  // K1T/K2T live in the out region (dead until k_gather, which runs after
  // both consumers have finished).
  float* k1t = out;                    // 40000 floats
  float* k2t = out + N12 * N12;        // 40000 floats

  k_transpose<<<dim3((N12 * N12 + 255) / 256), 256, 0, stream>>>(K1, K2, k1t, k2t);

  // contract i: T1 -> reg region (scratch)
  k_contract_i<<<dim3(SJK / 256, 4), 256, 0, stream>>>(TT, k1t, reg);

  const size_t need = (size_t)NTOT * sizeof(float);   // 256,000,000 B
  if (ws_size >= need) {
    float* T2 = (float*)d_ws;
    k_contract_j<<<dim3(5, N12, 4), 320, 0, stream>>>(reg, k2t, T2);
    k_gather<<<dim3(OUT_ELEMS / 256), 256, 0, stream>>>(T2, K3, idx, out);
    k_contract_k_reg<<<dim3(40000 * 32 / 256), 256, 0, stream>>>(T2, TT, K3, reg);
  } else {
    // in-place fallback: T2 overwrites T1 inside the reg region
    k_contract_j_inplace<<<dim3(20, N12), 256, 0, stream>>>(reg, k2t);
    k_gather<<<dim3(OUT_ELEMS / 256), 256, 0, stream>>>(reg, K3, idx, out);
    k_contract_k_reg<<<dim3(40000 * 32 / 256), 256, 0, stream>>>(reg, TT, K3, reg);
  }
}